// Round 5
// baseline (4306.622 us; speedup 1.0000x reference)
//
#include <hip/hip_runtime.h>
#include <stdint.h>

#define NN 8192
#define FIN 512
#define FOUT 256
#define ALPHA 0.2f
#define KSPLIT 8
#define KSLICE (NN / KSPLIT)   // 1024
#define BK 32
#define ITERS (KSLICE / BK)    // 32

typedef float f32x4 __attribute__((ext_vector_type(4)));
typedef short s16x8 __attribute__((ext_vector_type(8)));

__device__ __forceinline__ uint16_t f2bf(float f) {
  union { float f; uint32_t u; } v; v.f = f;
  uint32_t u = v.u + 0x7fffu + ((v.u >> 16) & 1u);
  return (uint16_t)(u >> 16);
}

// LDS-only barrier: waits DS ops, does NOT drain vmcnt -> global prefetches
// stay in flight across the barrier.
__device__ __forceinline__ void lds_barrier() {
  asm volatile("s_waitcnt lgkmcnt(0)\n\ts_barrier" ::: "memory");
}

// ---------------- 1. wa1/wa2 = W @ a1 / a2 (fp32) ----------------
__global__ __launch_bounds__(256) void k_wa(const float* __restrict__ W,
                                            const float* __restrict__ a,
                                            float* __restrict__ wa1, float* __restrict__ wa2) {
  __shared__ float a1[256], a2[256];
  int tid = threadIdx.x;
  a1[tid] = a[tid];
  a2[tid] = a[tid + 256];
  __syncthreads();
  int m = blockIdx.x * 256 + tid;   // 0..511
  const float* wrow = W + (size_t)m * FOUT;
  float s1 = 0.f, s2 = 0.f;
  for (int k = 0; k < FOUT; k += 4) {
    f32x4 v = *(const f32x4*)(wrow + k);
#pragma unroll
    for (int i = 0; i < 4; i++) {
      s1 += v[i] * a1[k + i];
      s2 += v[i] * a2[k + i];
    }
  }
  wa1[m] = s1; wa2[m] = s2;
}

// ---------------- 2. f1/f2 = x @ wa1/wa2 (fp32, exact logits) ----------------
__global__ __launch_bounds__(256) void k_f1f2(const float* __restrict__ x,
                                              const float* __restrict__ wa1,
                                              const float* __restrict__ wa2,
                                              float* __restrict__ f1, float* __restrict__ f2) {
  __shared__ float s1[512], s2[512];
  int tid = threadIdx.x;
  s1[tid] = wa1[tid]; s1[tid + 256] = wa1[tid + 256];
  s2[tid] = wa2[tid]; s2[tid + 256] = wa2[tid + 256];
  __syncthreads();
  int w = tid >> 6, l = tid & 63;
  int row = blockIdx.x * 4 + w;
  const float* xr = x + (size_t)row * FIN + l * 8;
  f32x4 v0 = *(const f32x4*)xr;
  f32x4 v1 = *(const f32x4*)(xr + 4);
  int kb = l * 8;
  float d1 = 0.f, d2 = 0.f;
#pragma unroll
  for (int i = 0; i < 4; i++) {
    d1 += v0[i] * s1[kb + i] + v1[i] * s1[kb + 4 + i];
    d2 += v0[i] * s2[kb + i] + v1[i] * s2[kb + 4 + i];
  }
#pragma unroll
  for (int off = 32; off; off >>= 1) {
    d1 += __shfl_down(d1, off);
    d2 += __shfl_down(d2, off);
  }
  if (l == 0) { f1[row] = d1; f2[row] = d2; }
}

// ---------------- 3. wt[f][k] = bf16(W[k][f]) ----------------
__global__ __launch_bounds__(256) void k_prep_wt(const float* __restrict__ W,
                                                 uint16_t* __restrict__ wt) {
  int idx = blockIdx.x * 256 + threadIdx.x;
  int f  = idx >> 7;
  int k4 = (idx & 127) * 4;
  ushort4 o;
  o.x = f2bf(W[(size_t)(k4 + 0) * FOUT + f]);
  o.y = f2bf(W[(size_t)(k4 + 1) * FOUT + f]);
  o.z = f2bf(W[(size_t)(k4 + 2) * FOUT + f]);
  o.w = f2bf(W[(size_t)(k4 + 3) * FOUT + f]);
  *(ushort4*)(wt + (size_t)f * FIN + k4) = o;
}

// ---------------- 4. ht = (x @ W)^T (bf16 MFMA) ----------------
__global__ __launch_bounds__(256, 2) void k_gemm_h(const float* __restrict__ x,
                                                   const uint16_t* __restrict__ wt,
                                                   uint16_t* __restrict__ ht) {
  __shared__ __align__(16) uint16_t Xs[64][40];
  __shared__ __align__(16) uint16_t Ws[128][40];
  int i0 = blockIdx.x * 64;
  int f0 = blockIdx.y * 128;
  int tid = threadIdx.x;
  int l = tid & 63, w = tid >> 6;
  int q = l >> 4, r16 = l & 15;
  f32x4 acc[4][2];
#pragma unroll
  for (int a = 0; a < 4; a++)
#pragma unroll
    for (int b = 0; b < 2; b++) acc[a][b] = (f32x4)0.f;

  int xr = tid >> 2, xc = (tid & 3) * 8;
  int wr = tid >> 1, wc = (tid & 1) * 16;
  const float* xp = x + (size_t)(i0 + xr) * FIN + xc;
  const uint16_t* wp = wt + (size_t)(f0 + wr) * FIN + wc;

  f32x4 u0 = *(const f32x4*)xp;
  f32x4 u1 = *(const f32x4*)(xp + 4);
  uint4 wA = *(const uint4*)wp;
  uint4 wB = *(const uint4*)(wp + 8);

  const int GI = FIN / BK;  // 16
  for (int s = 0; s < GI; s++) {
    int sn = (s + 1 < GI) ? (s + 1) : s;
    f32x4 u0n = *(const f32x4*)(xp + sn * BK);
    f32x4 u1n = *(const f32x4*)(xp + sn * BK + 4);
    uint4 wAn = *(const uint4*)(wp + sn * BK);
    uint4 wBn = *(const uint4*)(wp + sn * BK + 8);

    uint4 pk;
    pk.x = (uint32_t)f2bf(u0[0]) | ((uint32_t)f2bf(u0[1]) << 16);
    pk.y = (uint32_t)f2bf(u0[2]) | ((uint32_t)f2bf(u0[3]) << 16);
    pk.z = (uint32_t)f2bf(u1[0]) | ((uint32_t)f2bf(u1[1]) << 16);
    pk.w = (uint32_t)f2bf(u1[2]) | ((uint32_t)f2bf(u1[3]) << 16);
    *(uint4*)(&Xs[xr][xc]) = pk;
    *(uint4*)(&Ws[wr][wc]) = wA;
    *(uint4*)(&Ws[wr][wc + 8]) = wB;
    lds_barrier();

    s16x8 Af[4], Bf[2];
#pragma unroll
    for (int a = 0; a < 4; a++) Af[a] = *(const s16x8*)(&Xs[a * 16 + r16][q * 8]);
#pragma unroll
    for (int b = 0; b < 2; b++) Bf[b] = *(const s16x8*)(&Ws[w * 32 + b * 16 + r16][q * 8]);
#pragma unroll
    for (int a = 0; a < 4; a++)
#pragma unroll
      for (int b = 0; b < 2; b++)
        acc[a][b] = __builtin_amdgcn_mfma_f32_16x16x32_bf16(Af[a], Bf[b], acc[a][b], 0, 0, 0);
    lds_barrier();
    u0 = u0n; u1 = u1n; wA = wAn; wB = wBn;
  }

#pragma unroll
  for (int a = 0; a < 4; a++)
#pragma unroll
    for (int b = 0; b < 2; b++) {
      int f = f0 + w * 32 + b * 16 + r16;
      int i = i0 + a * 16 + q * 4;
      ushort4 o;
      o.x = f2bf(acc[a][b][0]); o.y = f2bf(acc[a][b][1]);
      o.z = f2bf(acc[a][b][2]); o.w = f2bf(acc[a][b][3]);
      *(ushort4*)(ht + (size_t)f * NN + i) = o;
    }
}

// ---------------- 5. zero the softmax denominators ----------------
__global__ __launch_bounds__(256) void k_zero(float* __restrict__ l_arr) {
  l_arr[blockIdx.x * 256 + threadIdx.x] = 0.f;
}

// ---------------- 6. fused scores -> P(bf16, LDS dbuf) -> P @ h (B direct from L2) ----------------
// 256 thr (4 waves). BM=64, BN=256 (wave w -> feats w*64..+63), BK=32, KSPLIT=8.
// Only Ps lives in LDS (10 KB dbuf). B-frags load global->VGPR (ht slice is L2-hot,
// shared by 32 row-blocks). adj + B pipelined 2 iterations ahead; one lds_barrier
// per iteration; no vmcnt drain anywhere in the loop.
__global__ __launch_bounds__(256, 3) void k_att(const int* __restrict__ adj,
                                                const uint16_t* __restrict__ ht,
                                                const float* __restrict__ f1,
                                                const float* __restrict__ f2,
                                                float* __restrict__ l_arr,
                                                float* __restrict__ part) {
  __shared__ __align__(16) uint16_t Ps[2][64][40];    // 10 KB
  __shared__ __align__(16) float Fs[KSLICE];          // 4 KB
  const int i0 = blockIdx.x * 64;
  const int jbase = blockIdx.y * KSLICE;
  const int tid = threadIdx.x;
  const int l = tid & 63, w = tid >> 6;
  const int q = l >> 4, r16 = l & 15;
  const int pr = tid >> 2, pc = tid & 3;

  *(f32x4*)(&Fs[tid * 4]) = *(const f32x4*)(f2 + jbase + tid * 4);

  const float f1i = f1[i0 + pr];
  float lsum = 0.f;
  f32x4 acc[4][4];
#pragma unroll
  for (int a = 0; a < 4; a++)
#pragma unroll
    for (int b = 0; b < 4; b++) acc[a][b] = (f32x4)0.f;

  const int* adjp = adj + (size_t)(i0 + pr) * NN + jbase + pc * 8;
  // per-lane B base: row = w*64 + r16 (+ b*16), col = jbase + q*8 (+ s*BK)
  const uint16_t* htb = ht + (size_t)(w * 64 + r16) * NN + jbase + q * 8;

  int4 adjR[2][2];
  s16x8 Bf[2][4];

#define LOADADJ(t, p) do {                                    \
    int t_ = (t) < ITERS ? (t) : (ITERS - 1);                 \
    const int* ap_ = adjp + t_ * BK;                          \
    adjR[p][0] = *(const int4*)ap_;                           \
    adjR[p][1] = *(const int4*)(ap_ + 4);                     \
  } while (0)

#define LOADB(t, p) do {                                      \
    int t_ = (t) < ITERS ? (t) : (ITERS - 1);                 \
    const uint16_t* hp_ = htb + t_ * BK;                      \
    _Pragma("unroll")                                         \
    for (int b_ = 0; b_ < 4; b_++)                            \
      Bf[p][b_] = *(const s16x8*)(hp_ + (size_t)(b_ * 16) * NN); \
  } while (0)

#define STAGE(t) do {                                         \
    int p_ = (t) & 1;                                         \
    f32x4 F0_ = *(const f32x4*)(&Fs[(t) * BK + pc * 8]);      \
    f32x4 F1_ = *(const f32x4*)(&Fs[(t) * BK + pc * 8 + 4]);  \
    const int* av_ = (const int*)&adjR[p_][0];                \
    s16x8 pv_;                                                \
    _Pragma("unroll")                                         \
    for (int i_ = 0; i_ < 8; i_++) {                          \
      float fj_ = (i_ < 4) ? F0_[i_] : F1_[i_ - 4];           \
      float s_ = f1i + fj_;                                   \
      float e_ = fmaxf(s_, ALPHA * s_);                       \
      float p2_ = (av_[i_] != 0) ? __expf(e_) : 1.0f;         \
      lsum += p2_;                                            \
      pv_[i_] = (short)f2bf(p2_);                             \
    }                                                         \
    *(s16x8*)(&Ps[p_][pr][pc * 8]) = pv_;                     \
  } while (0)

#define MFMA(t) do {                                          \
    int p_ = (t) & 1;                                         \
    s16x8 Af_[4];                                             \
    _Pragma("unroll")                                         \
    for (int a_ = 0; a_ < 4; a_++)                            \
      Af_[a_] = *(const s16x8*)(&Ps[p_][a_ * 16 + r16][q * 8]); \
    _Pragma("unroll")                                         \
    for (int a_ = 0; a_ < 4; a_++)                            \
      _Pragma("unroll")                                       \
      for (int b_ = 0; b_ < 4; b_++)                          \
        acc[a_][b_] = __builtin_amdgcn_mfma_f32_16x16x32_bf16(Af_[a_], Bf[p_][b_], acc[a_][b_], 0, 0, 0); \
  } while (0)

  // prologue
  LOADADJ(0, 0); LOADADJ(1, 1);
  LOADB(0, 0);   LOADB(1, 1);
  lds_barrier();            // Fs visible
  STAGE(0);
  LOADADJ(2, 0);
  lds_barrier();            // Ps[0] visible

  for (int s = 0; s < ITERS - 1; s++) {
    int par = s & 1, nxt = par ^ 1;
    MFMA(s);                // consumes Ps[par], Bf[par]
    LOADB(s + 2, par);      // Bf[par] now free; in flight ~2 iters
    STAGE(s + 1);           // consumes adjR[nxt], writes Ps[nxt]
    LOADADJ(s + 3, nxt);    // adjR[nxt] now free; in flight ~2 iters
    lds_barrier();          // Ps[nxt] visible; no vmcnt drain
  }
  MFMA(ITERS - 1);

#undef LOADADJ
#undef LOADB
#undef STAGE
#undef MFMA

  // denominator: reduce over the 4 lanes sharing pr, one atomic per row/block
  lsum += __shfl_down(lsum, 2);
  lsum += __shfl_down(lsum, 1);
  if (pc == 0) atomicAdd(&l_arr[i0 + pr], lsum);

  // row-major part [split][row][col] -> coalesced dword stores (r2/r3-proven)
  float* pb = part + (size_t)blockIdx.y * ((size_t)NN * FOUT);
#pragma unroll
  for (int a = 0; a < 4; a++)
#pragma unroll
    for (int b = 0; b < 4; b++)
#pragma unroll
      for (int reg = 0; reg < 4; reg++) {
        int row = i0 + a * 16 + q * 4 + reg;
        int col = w * 64 + b * 16 + r16;
        pb[(size_t)row * FOUT + col] = acc[a][b][reg];
      }
}

// ---------------- 7. combine split-K partials, /l, ELU, fp32 out ----------------
__global__ __launch_bounds__(256) void k_combine(const float* __restrict__ part,
                                                 const float* __restrict__ l_arr,
                                                 float* __restrict__ out) {
  int idx = (blockIdx.x * 256 + threadIdx.x) * 4;   // flat in [NN][FOUT]
  float r = 1.0f / l_arr[idx >> 8];
  f32x4 sum = (f32x4)0.f;
#pragma unroll
  for (int p = 0; p < KSPLIT; p++)
    sum += *(const f32x4*)(part + (size_t)p * NN * FOUT + idx);
  f32x4 o;
#pragma unroll
  for (int i = 0; i < 4; i++) {
    float v = sum[i] * r;
    o[i] = v > 0.f ? v : (__expf(v) - 1.f);
  }
  *(f32x4*)(out + idx) = o;
}

extern "C" void kernel_launch(void* const* d_in, const int* in_sizes, int n_in,
                              void* d_out, int out_size, void* d_ws, size_t ws_size,
                              hipStream_t stream) {
  const float* x   = (const float*)d_in[0];
  const int*   adj = (const int*)d_in[1];
  const float* W   = (const float*)d_in[2];
  const float* a   = (const float*)d_in[3];
  float* out = (float*)d_out;

  char* ws = (char*)d_ws;
  float*    wa1   = (float*)ws;                        // 512 f32
  float*    wa2   = wa1 + 512;                         // 512 f32
  float*    f1    = wa2 + 512;                         // 8192 f32
  float*    f2    = f1 + NN;                           // 8192 f32
  float*    l_arr = f2 + NN;                           // 8192 f32
  uint16_t* wt    = (uint16_t*)(l_arr + NN);           // 256*512 bf16
  uint16_t* ht    = wt + (size_t)FOUT * FIN;           // 256*8192 bf16 (4 MB)
  float*    part  = (float*)(ht + (size_t)NN * FOUT);  // KSPLIT * 8192*256 f32 (64 MB)

  k_wa<<<2, 256, 0, stream>>>(W, a, wa1, wa2);
  k_prep_wt<<<128, 256, 0, stream>>>(W, wt);
  k_f1f2<<<NN / 4, 256, 0, stream>>>(x, wa1, wa2, f1, f2);
  k_zero<<<NN / 256, 256, 0, stream>>>(l_arr);
  k_gemm_h<<<dim3(128, 2), 256, 0, stream>>>(x, wt, ht);
  k_att<<<dim3(NN / 64, KSPLIT), 256, 0, stream>>>(adj, ht, f1, f2, l_arr, part);
  k_combine<<<NN * FOUT / 1024, 256, 0, stream>>>(part, l_arr, out);
}

// Round 6
// 470.303 us; speedup vs baseline: 9.1571x; 9.1571x over previous
//
#include <hip/hip_runtime.h>
#include <stdint.h>

#define NN 8192
#define FIN 512
#define FOUT 256
#define ALPHA 0.2f
#define KSPLIT 8
#define KSLICE (NN / KSPLIT)   // 1024
#define BK 32
#define ITERS (KSLICE / BK)    // 32

typedef float f32x4 __attribute__((ext_vector_type(4)));
typedef short s16x8 __attribute__((ext_vector_type(8)));

__device__ __forceinline__ uint16_t f2bf(float f) {
  union { float f; uint32_t u; } v; v.f = f;
  uint32_t u = v.u + 0x7fffu + ((v.u >> 16) & 1u);
  return (uint16_t)(u >> 16);
}

// LDS-only barrier: waits DS ops, does NOT drain vmcnt -> global prefetches
// stay in flight across the barrier.
__device__ __forceinline__ void lds_barrier() {
  asm volatile("s_waitcnt lgkmcnt(0)\n\ts_barrier" ::: "memory");
}

// ---------------- 1. wa1/wa2 = W @ a1 / a2 (fp32) ----------------
__global__ __launch_bounds__(256) void k_wa(const float* __restrict__ W,
                                            const float* __restrict__ a,
                                            float* __restrict__ wa1, float* __restrict__ wa2) {
  __shared__ float a1[256], a2[256];
  int tid = threadIdx.x;
  a1[tid] = a[tid];
  a2[tid] = a[tid + 256];
  __syncthreads();
  int m = blockIdx.x * 256 + tid;   // 0..511
  const float* wrow = W + (size_t)m * FOUT;
  float s1 = 0.f, s2 = 0.f;
  for (int k = 0; k < FOUT; k += 4) {
    f32x4 v = *(const f32x4*)(wrow + k);
#pragma unroll
    for (int i = 0; i < 4; i++) {
      s1 += v[i] * a1[k + i];
      s2 += v[i] * a2[k + i];
    }
  }
  wa1[m] = s1; wa2[m] = s2;
}

// ---------------- 2. f1/f2 = x @ wa1/wa2 (fp32, exact logits) ----------------
__global__ __launch_bounds__(256) void k_f1f2(const float* __restrict__ x,
                                              const float* __restrict__ wa1,
                                              const float* __restrict__ wa2,
                                              float* __restrict__ f1, float* __restrict__ f2) {
  __shared__ float s1[512], s2[512];
  int tid = threadIdx.x;
  s1[tid] = wa1[tid]; s1[tid + 256] = wa1[tid + 256];
  s2[tid] = wa2[tid]; s2[tid + 256] = wa2[tid + 256];
  __syncthreads();
  int w = tid >> 6, l = tid & 63;
  int row = blockIdx.x * 4 + w;
  const float* xr = x + (size_t)row * FIN + l * 8;
  f32x4 v0 = *(const f32x4*)xr;
  f32x4 v1 = *(const f32x4*)(xr + 4);
  int kb = l * 8;
  float d1 = 0.f, d2 = 0.f;
#pragma unroll
  for (int i = 0; i < 4; i++) {
    d1 += v0[i] * s1[kb + i] + v1[i] * s1[kb + 4 + i];
    d2 += v0[i] * s2[kb + i] + v1[i] * s2[kb + 4 + i];
  }
#pragma unroll
  for (int off = 32; off; off >>= 1) {
    d1 += __shfl_down(d1, off);
    d2 += __shfl_down(d2, off);
  }
  if (l == 0) { f1[row] = d1; f2[row] = d2; }
}

// ---------------- 3. wt[f][k] = bf16(W[k][f]) ----------------
__global__ __launch_bounds__(256) void k_prep_wt(const float* __restrict__ W,
                                                 uint16_t* __restrict__ wt) {
  int idx = blockIdx.x * 256 + threadIdx.x;
  int f  = idx >> 7;
  int k4 = (idx & 127) * 4;
  ushort4 o;
  o.x = f2bf(W[(size_t)(k4 + 0) * FOUT + f]);
  o.y = f2bf(W[(size_t)(k4 + 1) * FOUT + f]);
  o.z = f2bf(W[(size_t)(k4 + 2) * FOUT + f]);
  o.w = f2bf(W[(size_t)(k4 + 3) * FOUT + f]);
  *(ushort4*)(wt + (size_t)f * FIN + k4) = o;
}

// ---------------- 4. ht = (x @ W)^T (bf16 MFMA) ----------------
__global__ __launch_bounds__(256, 2) void k_gemm_h(const float* __restrict__ x,
                                                   const uint16_t* __restrict__ wt,
                                                   uint16_t* __restrict__ ht) {
  __shared__ __align__(16) uint16_t Xs[64][40];
  __shared__ __align__(16) uint16_t Ws[128][40];
  int i0 = blockIdx.x * 64;
  int f0 = blockIdx.y * 128;
  int tid = threadIdx.x;
  int l = tid & 63, w = tid >> 6;
  int q = l >> 4, r16 = l & 15;
  f32x4 acc[4][2];
#pragma unroll
  for (int a = 0; a < 4; a++)
#pragma unroll
    for (int b = 0; b < 2; b++) acc[a][b] = (f32x4)0.f;

  int xr = tid >> 2, xc = (tid & 3) * 8;
  int wr = tid >> 1, wc = (tid & 1) * 16;
  const float* xp = x + (size_t)(i0 + xr) * FIN + xc;
  const uint16_t* wp = wt + (size_t)(f0 + wr) * FIN + wc;

  f32x4 u0 = *(const f32x4*)xp;
  f32x4 u1 = *(const f32x4*)(xp + 4);
  uint4 wA = *(const uint4*)wp;
  uint4 wB = *(const uint4*)(wp + 8);

  const int GI = FIN / BK;  // 16
  for (int s = 0; s < GI; s++) {
    int sn = (s + 1 < GI) ? (s + 1) : s;
    f32x4 u0n = *(const f32x4*)(xp + sn * BK);
    f32x4 u1n = *(const f32x4*)(xp + sn * BK + 4);
    uint4 wAn = *(const uint4*)(wp + sn * BK);
    uint4 wBn = *(const uint4*)(wp + sn * BK + 8);

    uint4 pk;
    pk.x = (uint32_t)f2bf(u0[0]) | ((uint32_t)f2bf(u0[1]) << 16);
    pk.y = (uint32_t)f2bf(u0[2]) | ((uint32_t)f2bf(u0[3]) << 16);
    pk.z = (uint32_t)f2bf(u1[0]) | ((uint32_t)f2bf(u1[1]) << 16);
    pk.w = (uint32_t)f2bf(u1[2]) | ((uint32_t)f2bf(u1[3]) << 16);
    *(uint4*)(&Xs[xr][xc]) = pk;
    *(uint4*)(&Ws[wr][wc]) = wA;
    *(uint4*)(&Ws[wr][wc + 8]) = wB;
    lds_barrier();

    s16x8 Af[4], Bf[2];
#pragma unroll
    for (int a = 0; a < 4; a++) Af[a] = *(const s16x8*)(&Xs[a * 16 + r16][q * 8]);
#pragma unroll
    for (int b = 0; b < 2; b++) Bf[b] = *(const s16x8*)(&Ws[w * 32 + b * 16 + r16][q * 8]);
#pragma unroll
    for (int a = 0; a < 4; a++)
#pragma unroll
      for (int b = 0; b < 2; b++)
        acc[a][b] = __builtin_amdgcn_mfma_f32_16x16x32_bf16(Af[a], Bf[b], acc[a][b], 0, 0, 0);
    lds_barrier();
    u0 = u0n; u1 = u1n; wA = wAn; wB = wBn;
  }

#pragma unroll
  for (int a = 0; a < 4; a++)
#pragma unroll
    for (int b = 0; b < 2; b++) {
      int f = f0 + w * 32 + b * 16 + r16;
      int i = i0 + a * 16 + q * 4;
      ushort4 o;
      o.x = f2bf(acc[a][b][0]); o.y = f2bf(acc[a][b][1]);
      o.z = f2bf(acc[a][b][2]); o.w = f2bf(acc[a][b][3]);
      *(ushort4*)(ht + (size_t)f * NN + i) = o;
    }
}

// ---------------- 5. zero the softmax denominators ----------------
__global__ __launch_bounds__(256) void k_zero(float* __restrict__ l_arr) {
  l_arr[blockIdx.x * 256 + threadIdx.x] = 0.f;
}

// ---------------- 6. fused scores -> P(bf16, LDS dbuf) -> P @ h (B from L2) ----------------
// Same pipeline as r5 but with COMPILE-TIME buffer parity: explicit Bf0/Bf1,
// adjR0/adjR1 and a hand-unrolled x2 steady loop -> no dynamic VGPR-array
// indexing -> no scratch spills (r5: 4.7 GB scratch traffic from runtime parity).
__global__ __launch_bounds__(256, 3) void k_att(const int* __restrict__ adj,
                                                const uint16_t* __restrict__ ht,
                                                const float* __restrict__ f1,
                                                const float* __restrict__ f2,
                                                float* __restrict__ l_arr,
                                                float* __restrict__ part) {
  __shared__ __align__(16) uint16_t Ps[2][64][40];    // 10 KB
  __shared__ __align__(16) float Fs[KSLICE];          // 4 KB
  const int i0 = blockIdx.x * 64;
  const int jbase = blockIdx.y * KSLICE;
  const int tid = threadIdx.x;
  const int l = tid & 63, w = tid >> 6;
  const int q = l >> 4, r16 = l & 15;
  const int pr = tid >> 2, pc = tid & 3;

  *(f32x4*)(&Fs[tid * 4]) = *(const f32x4*)(f2 + jbase + tid * 4);

  const float f1i = f1[i0 + pr];
  float lsum = 0.f;
  f32x4 acc[4][4];
#pragma unroll
  for (int a = 0; a < 4; a++)
#pragma unroll
    for (int b = 0; b < 4; b++) acc[a][b] = (f32x4)0.f;

  const int* adjp = adj + (size_t)(i0 + pr) * NN + jbase + pc * 8;
  const uint16_t* htb = ht + (size_t)(w * 64 + r16) * NN + jbase + q * 8;

  int4 adjR0[2], adjR1[2];
  s16x8 Bf0[4], Bf1[4];

#define LOADADJ(t, R) do {                                    \
    int t_ = ((t) < ITERS) ? (t) : (ITERS - 1);               \
    const int* ap_ = adjp + t_ * BK;                          \
    R[0] = *(const int4*)ap_;                                 \
    R[1] = *(const int4*)(ap_ + 4);                           \
  } while (0)

#define LOADB(t, B) do {                                      \
    int t_ = ((t) < ITERS) ? (t) : (ITERS - 1);               \
    const uint16_t* hp_ = htb + t_ * BK;                      \
    B[0] = *(const s16x8*)(hp_);                              \
    B[1] = *(const s16x8*)(hp_ + (size_t)16 * NN);            \
    B[2] = *(const s16x8*)(hp_ + (size_t)32 * NN);            \
    B[3] = *(const s16x8*)(hp_ + (size_t)48 * NN);            \
  } while (0)

#define STAGE(t, R, buf) do {                                 \
    f32x4 F0_ = *(const f32x4*)(&Fs[(t) * BK + pc * 8]);      \
    f32x4 F1_ = *(const f32x4*)(&Fs[(t) * BK + pc * 8 + 4]);  \
    const int* av_ = (const int*)&R[0];                       \
    s16x8 pv_;                                                \
    _Pragma("unroll")                                         \
    for (int i_ = 0; i_ < 8; i_++) {                          \
      float fj_ = (i_ < 4) ? F0_[i_] : F1_[i_ - 4];           \
      float s_ = f1i + fj_;                                   \
      float e_ = fmaxf(s_, ALPHA * s_);                       \
      float p2_ = (av_[i_] != 0) ? __expf(e_) : 1.0f;         \
      lsum += p2_;                                            \
      pv_[i_] = (short)f2bf(p2_);                             \
    }                                                         \
    *(s16x8*)(&Ps[buf][pr][pc * 8]) = pv_;                    \
  } while (0)

#define MFMA_(B, buf) do {                                    \
    s16x8 Af_[4];                                             \
    _Pragma("unroll")                                         \
    for (int a_ = 0; a_ < 4; a_++)                            \
      Af_[a_] = *(const s16x8*)(&Ps[buf][a_ * 16 + r16][q * 8]); \
    _Pragma("unroll")                                         \
    for (int a_ = 0; a_ < 4; a_++)                            \
      _Pragma("unroll")                                       \
      for (int b_ = 0; b_ < 4; b_++)                          \
        acc[a_][b_] = __builtin_amdgcn_mfma_f32_16x16x32_bf16(Af_[a_], B[b_], acc[a_][b_], 0, 0, 0); \
  } while (0)

  // prologue
  LOADADJ(0, adjR0); LOADADJ(1, adjR1);
  LOADB(0, Bf0);     LOADB(1, Bf1);
  lds_barrier();            // Fs visible
  STAGE(0, adjR0, 0);
  LOADADJ(2, adjR0);
  lds_barrier();            // Ps[0] visible

  // steady state, parity fully compile-time
  for (int s = 0; s < ITERS - 2; s += 2) {
    MFMA_(Bf0, 0);          // consumes Ps[0], Bf0
    LOADB(s + 2, Bf0);      // refill Bf0, ~2 iters in flight
    STAGE(s + 1, adjR1, 1); // adjR1 -> Ps[1]
    LOADADJ(s + 3, adjR1);
    lds_barrier();          // Ps[1] visible; no vmcnt drain

    MFMA_(Bf1, 1);
    LOADB(s + 3, Bf1);
    STAGE(s + 2, adjR0, 0); // adjR0 -> Ps[0]
    LOADADJ(s + 4, adjR0);
    lds_barrier();          // Ps[0] visible
  }
  MFMA_(Bf0, 0);            // t = ITERS-2
  STAGE(ITERS - 1, adjR1, 1);
  lds_barrier();
  MFMA_(Bf1, 1);            // t = ITERS-1

#undef LOADADJ
#undef LOADB
#undef STAGE
#undef MFMA_

  // denominator: reduce over the 4 lanes sharing pr, one atomic per row/block
  lsum += __shfl_down(lsum, 2);
  lsum += __shfl_down(lsum, 1);
  if (pc == 0) atomicAdd(&l_arr[i0 + pr], lsum);

  // row-major part [split][row][col] -> coalesced dword stores
  float* pb = part + (size_t)blockIdx.y * ((size_t)NN * FOUT);
#pragma unroll
  for (int a = 0; a < 4; a++)
#pragma unroll
    for (int b = 0; b < 4; b++)
#pragma unroll
      for (int reg = 0; reg < 4; reg++) {
        int row = i0 + a * 16 + q * 4 + reg;
        int col = w * 64 + b * 16 + r16;
        pb[(size_t)row * FOUT + col] = acc[a][b][reg];
      }
}

// ---------------- 7. combine split-K partials, /l, ELU, fp32 out ----------------
__global__ __launch_bounds__(256) void k_combine(const float* __restrict__ part,
                                                 const float* __restrict__ l_arr,
                                                 float* __restrict__ out) {
  int idx = (blockIdx.x * 256 + threadIdx.x) * 4;   // flat in [NN][FOUT]
  float r = 1.0f / l_arr[idx >> 8];
  f32x4 sum = (f32x4)0.f;
#pragma unroll
  for (int p = 0; p < KSPLIT; p++)
    sum += *(const f32x4*)(part + (size_t)p * NN * FOUT + idx);
  f32x4 o;
#pragma unroll
  for (int i = 0; i < 4; i++) {
    float v = sum[i] * r;
    o[i] = v > 0.f ? v : (__expf(v) - 1.f);
  }
  *(f32x4*)(out + idx) = o;
}

extern "C" void kernel_launch(void* const* d_in, const int* in_sizes, int n_in,
                              void* d_out, int out_size, void* d_ws, size_t ws_size,
                              hipStream_t stream) {
  const float* x   = (const float*)d_in[0];
  const int*   adj = (const int*)d_in[1];
  const float* W   = (const float*)d_in[2];
  const float* a   = (const float*)d_in[3];
  float* out = (float*)d_out;

  char* ws = (char*)d_ws;
  float*    wa1   = (float*)ws;                        // 512 f32
  float*    wa2   = wa1 + 512;                         // 512 f32
  float*    f1    = wa2 + 512;                         // 8192 f32
  float*    f2    = f1 + NN;                           // 8192 f32
  float*    l_arr = f2 + NN;                           // 8192 f32
  uint16_t* wt    = (uint16_t*)(l_arr + NN);           // 256*512 bf16
  uint16_t* ht    = wt + (size_t)FOUT * FIN;           // 256*8192 bf16 (4 MB)
  float*    part  = (float*)(ht + (size_t)NN * FOUT);  // KSPLIT * 8192*256 f32 (64 MB)

  k_wa<<<2, 256, 0, stream>>>(W, a, wa1, wa2);
  k_prep_wt<<<128, 256, 0, stream>>>(W, wt);
  k_f1f2<<<NN / 4, 256, 0, stream>>>(x, wa1, wa2, f1, f2);
  k_zero<<<NN / 256, 256, 0, stream>>>(l_arr);
  k_gemm_h<<<dim3(128, 2), 256, 0, stream>>>(x, wt, ht);
  k_att<<<dim3(NN / 64, KSPLIT), 256, 0, stream>>>(adj, ht, f1, f2, l_arr, part);
  k_combine<<<NN * FOUT / 1024, 256, 0, stream>>>(part, l_arr, out);
}